// Round 1
// baseline (74.172 us; speedup 1.0000x reference)
//
#include <hip/hip_runtime.h>

// Problem constants (match reference)
constexpr int B  = 4;
constexpr int C  = 3;
constexpr int F  = 5;
constexpr int HO = 256;
constexpr int WO = 256;
constexpr int HI = HO + F - 1; // 260
constexpr int WI = WO + F - 1; // 260
constexpr int P  = HO * WO;    // 65536 pixels per (b, map)

__global__ __launch_bounds__(256) void dsepconv_kernel(
    const float* __restrict__ inp,   // (B, C, HI, WI)
    const float* __restrict__ vert,  // (B, F, HO, WO)
    const float* __restrict__ horz,  // (B, F, HO, WO)
    const float* __restrict__ offX,  // (B, F*F, HO, WO)  -> used for py
    const float* __restrict__ offY,  // (B, F*F, HO, WO)  -> used for px
    const float* __restrict__ mask,  // (B, F*F, HO, WO)
    float* __restrict__ out)         // (B, C, HO, WO)
{
    int idx = blockIdx.x * blockDim.x + threadIdx.x; // over B*HO*WO
    // B*HO*WO = 262144, grid sized exactly
    int x = idx & (WO - 1);
    int y = (idx >> 8) & (HO - 1);
    int b = idx >> 16;

    int pix = y * WO + x;
    const float* offXb = offX + (size_t)b * F * F * P + pix;
    const float* offYb = offY + (size_t)b * F * F * P + pix;
    const float* maskb = mask + (size_t)b * F * F * P + pix;
    const float* vb    = vert + (size_t)b * F * P + pix;
    const float* hb    = horz + (size_t)b * F * P + pix;
    const float* in0   = inp  + (size_t)b * C * HI * WI;
    const float* in1   = in0 + HI * WI;
    const float* in2   = in1 + HI * WI;

    float vv[F], hh[F];
#pragma unroll
    for (int i = 0; i < F; ++i) {
        vv[i] = vb[i * P];
        hh[i] = hb[i * P];
    }

    float acc0 = 0.f, acc1 = 0.f, acc2 = 0.f;

#pragma unroll
    for (int i = 0; i < F; ++i) {
#pragma unroll
        for (int j = 0; j < F; ++j) {
            const int k = i * F + j;
            float oy = offYb[k * P]; // -> px (horizontal), per reference
            float ox = offXb[k * P]; // -> py (vertical), per reference
            float m  = maskb[k * P];

            // px = clip(offY + x + j - half + 1, 0, WI-1); half = 2
            float px = oy + (float)(x + j - 1);
            px = fminf(fmaxf(px, 0.0f), (float)(WI - 1));
            float py = ox + (float)(y + i - 1);
            py = fminf(fmaxf(py, 0.0f), (float)(HI - 1));

            float lf = floorf(px);
            float tf = floorf(py);
            int l = (int)lf;
            int t = (int)tf;
            int r  = min(l + 1, WI - 1);
            int bt = min(t + 1, HI - 1);
            float wx = 1.0f - (px - lf);
            float wy = 1.0f - (py - tf);

            float w = vv[i] * hh[j] * m;
            float wtl = wx * wy * w;
            float wtr = (1.0f - wx) * wy * w;
            float wbl = wx * (1.0f - wy) * w;
            float wbr = (1.0f - wx) * (1.0f - wy) * w;

            int o_tl = t * WI + l;
            int o_tr = t * WI + r;
            int o_bl = bt * WI + l;
            int o_br = bt * WI + r;

            acc0 += in0[o_tl] * wtl + in0[o_tr] * wtr + in0[o_bl] * wbl + in0[o_br] * wbr;
            acc1 += in1[o_tl] * wtl + in1[o_tr] * wtr + in1[o_bl] * wbl + in1[o_br] * wbr;
            acc2 += in2[o_tl] * wtl + in2[o_tr] * wtr + in2[o_bl] * wbl + in2[o_br] * wbr;
        }
    }

    float* ob = out + (size_t)b * C * P + pix;
    ob[0]     = acc0;
    ob[P]     = acc1;
    ob[2 * P] = acc2;
}

extern "C" void kernel_launch(void* const* d_in, const int* in_sizes, int n_in,
                              void* d_out, int out_size, void* d_ws, size_t ws_size,
                              hipStream_t stream) {
    const float* inp  = (const float*)d_in[0];
    const float* vert = (const float*)d_in[1];
    const float* horz = (const float*)d_in[2];
    const float* offX = (const float*)d_in[3];
    const float* offY = (const float*)d_in[4];
    const float* mask = (const float*)d_in[5];
    float* out = (float*)d_out;

    const int total = B * HO * WO; // 262144
    dim3 block(256);
    dim3 grid(total / 256); // 1024
    dsepconv_kernel<<<grid, block, 0, stream>>>(inp, vert, horz, offX, offY, mask, out);
}

// Round 2
// 64.934 us; speedup vs baseline: 1.1423x; 1.1423x over previous
//
#include <hip/hip_runtime.h>

// Problem constants (match reference)
constexpr int B  = 4;
constexpr int C  = 3;
constexpr int F  = 5;
constexpr int HO = 256;
constexpr int WO = 256;
constexpr int HI = HO + F - 1; // 260
constexpr int WI = WO + F - 1; // 260
constexpr int P  = HO * WO;    // 65536 pixels per (b, map)
constexpr int FF = F * F;      // 25

// Grid gives 16 waves/CU (50% occ). VGPR pool allows 128 VGPR at 4 waves/SIMD,
// so register-heavy prefetch is free — batch all streaming loads up front for MLP.
__global__ __launch_bounds__(256, 4) void dsepconv_kernel(
    const float* __restrict__ inp,   // (B, C, HI, WI)
    const float* __restrict__ vert,  // (B, F, HO, WO)
    const float* __restrict__ horz,  // (B, F, HO, WO)
    const float* __restrict__ offX,  // (B, F*F, HO, WO)  -> used for py (vertical)
    const float* __restrict__ offY,  // (B, F*F, HO, WO)  -> used for px (horizontal)
    const float* __restrict__ mask,  // (B, F*F, HO, WO)
    float* __restrict__ out)         // (B, C, HO, WO)
{
    int idx = blockIdx.x * blockDim.x + threadIdx.x; // over B*HO*WO
    int x = idx & (WO - 1);
    int y = (idx >> 8) & (HO - 1);
    int b = idx >> 16;

    int pix = y * WO + x;
    const float* offXb = offX + (size_t)b * FF * P + pix;
    const float* offYb = offY + (size_t)b * FF * P + pix;
    const float* maskb = mask + (size_t)b * FF * P + pix;
    const float* vb    = vert + (size_t)b * F * P + pix;
    const float* hb    = horz + (size_t)b * F * P + pix;
    const float* in0   = inp  + (size_t)b * C * HI * WI;
    const float* in1   = in0 + HI * WI;
    const float* in2   = in1 + HI * WI;

    // ---- Batched streaming prefetch: 85 independent loads issued up front ----
    float oy[FF], ox[FF], mk[FF];
#pragma unroll
    for (int k = 0; k < FF; ++k) oy[k] = offYb[k * P];
#pragma unroll
    for (int k = 0; k < FF; ++k) ox[k] = offXb[k * P];
#pragma unroll
    for (int k = 0; k < FF; ++k) mk[k] = maskb[k * P];

    float vv[F], hh[F];
#pragma unroll
    for (int i = 0; i < F; ++i) {
        vv[i] = vb[i * P];
        hh[i] = hb[i * P];
    }

    float acc0 = 0.f, acc1 = 0.f, acc2 = 0.f;

#pragma unroll
    for (int i = 0; i < F; ++i) {
#pragma unroll
        for (int j = 0; j < F; ++j) {
            const int k = i * F + j;

            // px = clip(offY + x + j - half + 1, 0, WI-1); half = 2
            float px = oy[k] + (float)(x + j - 1);
            px = fminf(fmaxf(px, 0.0f), (float)(WI - 1));
            float py = ox[k] + (float)(y + i - 1);
            py = fminf(fmaxf(py, 0.0f), (float)(HI - 1));

            float lf = floorf(px);
            float tf = floorf(py);
            int l = (int)lf;
            int t = (int)tf;
            int r  = min(l + 1, WI - 1);
            int bt = min(t + 1, HI - 1);
            float wx = 1.0f - (px - lf);
            float wy = 1.0f - (py - tf);

            float w = vv[i] * hh[j] * mk[k];
            float wtl = wx * wy * w;
            float wtr = (1.0f - wx) * wy * w;
            float wbl = wx * (1.0f - wy) * w;
            float wbr = (1.0f - wx) * (1.0f - wy) * w;

            int o_tl = t * WI + l;
            int o_tr = t * WI + r;
            int o_bl = bt * WI + l;
            int o_br = bt * WI + r;

            // 12 independent gathers per tap; offsets all in regs so the
            // scheduler can hoist loads across taps.
            float a_tl = in0[o_tl], a_tr = in0[o_tr], a_bl = in0[o_bl], a_br = in0[o_br];
            float b_tl = in1[o_tl], b_tr = in1[o_tr], b_bl = in1[o_bl], b_br = in1[o_br];
            float c_tl = in2[o_tl], c_tr = in2[o_tr], c_bl = in2[o_bl], c_br = in2[o_br];

            acc0 += a_tl * wtl + a_tr * wtr + a_bl * wbl + a_br * wbr;
            acc1 += b_tl * wtl + b_tr * wtr + b_bl * wbl + b_br * wbr;
            acc2 += c_tl * wtl + c_tr * wtr + c_bl * wbl + c_br * wbr;
        }
    }

    float* ob = out + (size_t)b * C * P + pix;
    ob[0]     = acc0;
    ob[P]     = acc1;
    ob[2 * P] = acc2;
}

extern "C" void kernel_launch(void* const* d_in, const int* in_sizes, int n_in,
                              void* d_out, int out_size, void* d_ws, size_t ws_size,
                              hipStream_t stream) {
    const float* inp  = (const float*)d_in[0];
    const float* vert = (const float*)d_in[1];
    const float* horz = (const float*)d_in[2];
    const float* offX = (const float*)d_in[3];
    const float* offY = (const float*)d_in[4];
    const float* mask = (const float*)d_in[5];
    float* out = (float*)d_out;

    const int total = B * HO * WO; // 262144
    dim3 block(256);
    dim3 grid(total / 256); // 1024
    dsepconv_kernel<<<grid, block, 0, stream>>>(inp, vert, horz, offX, offY, mask, out);
}